// Round 4
// baseline (187.139 us; speedup 1.0000x reference)
//
#include <hip/hip_runtime.h>

// PCLLoss: C=256 classes, N=64 samples/class, D=1024.
// loss = mean_i [ sum_c ( log(eps + S_{i,c}) - pred[i,c] ) ]
// pred = Mv Mv^T, true = Mt Mt^T, Mv/Mt = per-class means of L2-normalized
// rows; S_{i,c} = sum_j exp(pred[i,j]) over j ranked at-or-after c in a
// stable descending sort of true[i,:]  (computed sort-free via an O(C) scan).
//
// R4: k1 with PARTS=4 (2048 blocks -> 8 blocks/CU, the 32-wave/CU cap) and
// 2-row register batches (8 live float4 = 32 VGPR; total ~58 <= 64 so we keep
// 32 waves/CU). R3's 512-block / 16-float4-batch variant sat at 18% occupancy
// with VGPR=40 (compiler serialized the loads) -> 50 us, latency-bound.

#define CC 256
#define NN 64
#define DD 1024
#define PARTS 4
#define TK 128   // K-slice for gram split-K

// ---------------- K1: normalize + partial class sums ------------------
// grid = 2*CC*PARTS = 2048 blocks x 256 thr. Block (t,c,p) handles 16 rows;
// each wave 4 rows in 2 batches of 2 (interleaved butterflies for ILP).
__global__ __launch_bounds__(256) void k1_partial(
    const float* __restrict__ emb, const float* __restrict__ feat,
    float* __restrict__ parts /* [2][CC][PARTS][DD] */, float* __restrict__ out)
{
    if (blockIdx.x == 0 && threadIdx.x == 0) out[0] = 0.f;  // for k3b atomics

    int b = blockIdx.x;
    int t = b >> 10;              // tensor
    int c = (b >> 2) & 255;       // class
    int p = b & 3;                // part (16 rows)
    const float* src = (t == 0 ? emb : feat) + ((size_t)c * NN + p * 16) * DD;
    int wave = threadIdx.x >> 6, lane = threadIdx.x & 63;

    float4 acc[4];
    #pragma unroll
    for (int k = 0; k < 4; ++k) acc[k] = make_float4(0.f, 0.f, 0.f, 0.f);

    #pragma unroll
    for (int batch = 0; batch < 2; ++batch) {
        const float* base = src + (size_t)(wave * 4 + batch * 2) * DD;
        float4 v[2][4];
        #pragma unroll
        for (int j = 0; j < 2; ++j)
            #pragma unroll
            for (int k = 0; k < 4; ++k)
                v[j][k] = *(const float4*)(base + (size_t)j * DD + k * 256 + lane * 4);

        float ss[2];
        #pragma unroll
        for (int j = 0; j < 2; ++j) {
            ss[j] = 0.f;
            #pragma unroll
            for (int k = 0; k < 4; ++k)
                ss[j] += v[j][k].x * v[j][k].x + v[j][k].y * v[j][k].y +
                         v[j][k].z * v[j][k].z + v[j][k].w * v[j][k].w;
        }
        #pragma unroll
        for (int m = 32; m >= 1; m >>= 1) {
            ss[0] += __shfl_xor(ss[0], m, 64);
            ss[1] += __shfl_xor(ss[1], m, 64);
        }
        #pragma unroll
        for (int j = 0; j < 2; ++j) {
            float inv = 1.0f / fmaxf(sqrtf(ss[j]), 1e-12f);  // F.normalize eps
            #pragma unroll
            for (int k = 0; k < 4; ++k) {
                acc[k].x += v[j][k].x * inv; acc[k].y += v[j][k].y * inv;
                acc[k].z += v[j][k].z * inv; acc[k].w += v[j][k].w * inv;
            }
        }
    }

    // combine the 4 waves via LDS, write partial sums
    __shared__ float lds[4][DD];  // 16 KB -> LDS allows 10 blocks/CU, not binding
    #pragma unroll
    for (int k = 0; k < 4; ++k)
        *(float4*)&lds[wave][k * 256 + lane * 4] = acc[k];
    __syncthreads();

    int col = threadIdx.x * 4;
    float4 s = *(float4*)&lds[0][col];
    #pragma unroll
    for (int w = 1; w < 4; ++w) {
        float4 x = *(float4*)&lds[w][col];
        s.x += x.x; s.y += x.y; s.z += x.z; s.w += x.w;
    }
    *(float4*)(parts + (((size_t)t * CC + c) * PARTS + p) * DD + col) = s;
}

// ---------------- K2: combine partials -> class means -----------------
__global__ __launch_bounds__(256) void k2_combine(
    const float* __restrict__ parts, float* __restrict__ means /* [2][CC][DD] */)
{
    size_t base = (size_t)blockIdx.x * PARTS * DD;
    int col = threadIdx.x * 4;
    float4 s = *(const float4*)(parts + base + col);
    #pragma unroll
    for (int p = 1; p < PARTS; ++p) {
        float4 x = *(const float4*)(parts + base + (size_t)p * DD + col);
        s.x += x.x; s.y += x.y; s.z += x.z; s.w += x.w;
    }
    const float invN = 1.0f / (float)NN;
    s.x *= invN; s.y *= invN; s.z *= invN; s.w *= invN;
    *(float4*)(means + (size_t)blockIdx.x * DD + col) = s;
}

// ---------------- K3a: split-K tiled Gram partials --------------------
// grid = 2 tensors * 16 tiles(64x64) * 8 K-splits = 256 blocks, 256 thr.
__global__ __launch_bounds__(256) void k3a_gram(
    const float* __restrict__ means, float* __restrict__ gpart /* [2][8][CC][CC] */)
{
    __shared__ float As[64][132];
    __shared__ float Bs[TK][68];

    int b = blockIdx.x;
    int t = b >> 7;
    int r = b & 127;
    int ks = r >> 4;
    int ti = (r >> 2) & 3, tj = r & 3;
    int i0 = ti * 64, j0 = tj * 64, k0 = ks * TK;
    const float* M = means + (size_t)t * CC * DD;

    for (int f = threadIdx.x; f < 64 * 32; f += 256) {
        int row = f >> 5, c4 = f & 31;
        float4 v = *(const float4*)(M + (size_t)(i0 + row) * DD + k0 + c4 * 4);
        *(float4*)&As[row][c4 * 4] = v;
    }
    for (int f = threadIdx.x; f < 64 * 32; f += 256) {
        int row = f >> 5, c4 = f & 31;
        float4 v = *(const float4*)(M + (size_t)(j0 + row) * DD + k0 + c4 * 4);
        Bs[c4 * 4 + 0][row] = v.x;
        Bs[c4 * 4 + 1][row] = v.y;
        Bs[c4 * 4 + 2][row] = v.z;
        Bs[c4 * 4 + 3][row] = v.w;
    }
    __syncthreads();

    int tr = threadIdx.x >> 4, tc = threadIdx.x & 15;
    float acc[4][4] = {};
    #pragma unroll 4
    for (int kk = 0; kk < TK; kk += 4) {
        float4 a[4], bb[4];
        #pragma unroll
        for (int q = 0; q < 4; ++q) a[q] = *(float4*)&As[tr * 4 + q][kk];
        #pragma unroll
        for (int kq = 0; kq < 4; ++kq) bb[kq] = *(float4*)&Bs[kk + kq][tc * 4];
        #pragma unroll
        for (int q = 0; q < 4; ++q) {
            acc[q][0] += a[q].x * bb[0].x + a[q].y * bb[1].x + a[q].z * bb[2].x + a[q].w * bb[3].x;
            acc[q][1] += a[q].x * bb[0].y + a[q].y * bb[1].y + a[q].z * bb[2].y + a[q].w * bb[3].y;
            acc[q][2] += a[q].x * bb[0].z + a[q].y * bb[1].z + a[q].z * bb[2].z + a[q].w * bb[3].z;
            acc[q][3] += a[q].x * bb[0].w + a[q].y * bb[1].w + a[q].z * bb[2].w + a[q].w * bb[3].w;
        }
    }

    float* G = gpart + (((size_t)(t * 8 + ks) * CC) + i0 + tr * 4) * CC + j0 + tc * 4;
    #pragma unroll
    for (int q = 0; q < 4; ++q)
        *(float4*)(G + (size_t)q * CC) =
            make_float4(acc[q][0], acc[q][1], acc[q][2], acc[q][3]);
}

// ---------------- K3b: reduce partials + ListMLE + final mean ---------
// grid = CC blocks; one atomicAdd per block into out (zeroed by k1).
__global__ __launch_bounds__(256) void k3b_listmle(
    const float* __restrict__ gpart, float* __restrict__ out)
{
    int i = blockIdx.x, c = threadIdx.x;
    float dp = 0.f, dt = 0.f;
    #pragma unroll
    for (int ks = 0; ks < 8; ++ks) {
        dp += gpart[((size_t)ks * CC + i) * CC + c];
        dt += gpart[((size_t)(8 + ks) * CC + i) * CC + c];
    }

    __shared__ float s_true[CC];
    __shared__ float s_pexp[CC];
    s_true[c] = dt;
    s_pexp[c] = expf(dp);
    __syncthreads();

    // S = sum exp(pred_j) over j ranked at-or-after c (stable desc by true)
    float S = 0.f;
    for (int j = 0; j < CC; ++j) {
        float tj = s_true[j];
        bool take = (tj < dt) || (tj == dt && j >= c);
        S += take ? s_pexp[j] : 0.f;
    }
    float contrib = logf(S + 1e-10f) - dp;

    #pragma unroll
    for (int m = 32; m >= 1; m >>= 1)
        contrib += __shfl_xor(contrib, m, 64);
    __shared__ float s_red[4];
    if ((c & 63) == 0) s_red[c >> 6] = contrib;
    __syncthreads();
    if (c == 0)
        atomicAdd(out, (s_red[0] + s_red[1] + s_red[2] + s_red[3]) * (1.0f / (float)CC));
}

extern "C" void kernel_launch(void* const* d_in, const int* in_sizes, int n_in,
                              void* d_out, int out_size, void* d_ws, size_t ws_size,
                              hipStream_t stream) {
    const float* emb  = (const float*)d_in[0];
    const float* feat = (const float*)d_in[1];
    float* ws = (float*)d_ws;
    float* parts = ws;                                  // 2*CC*PARTS*DD = 8 MiB
    float* means = parts + (size_t)2 * CC * PARTS * DD; // 2*CC*DD = 2 MiB
    float* gpart = means + (size_t)2 * CC * DD;         // 2*8*CC*CC = 4 MiB

    k1_partial <<<2 * CC * PARTS, 256, 0, stream>>>(emb, feat, parts, (float*)d_out);
    k2_combine <<<2 * CC, 256, 0, stream>>>(parts, means);
    k3a_gram   <<<256, 256, 0, stream>>>(means, gpart);
    k3b_listmle<<<CC, 256, 0, stream>>>(gpart, (float*)d_out);
}

// Round 5
// 184.166 us; speedup vs baseline: 1.0161x; 1.0161x over previous
//
#include <hip/hip_runtime.h>

// PCLLoss: C=256 classes, N=64 samples/class, D=1024.
// loss = mean_i [ sum_c ( log(eps + S_{i,c}) - pred[i,c] ) ]
// pred = Mv Mv^T, true = Mt Mt^T, Mv/Mt = per-class means of L2-normalized
// rows; S_{i,c} = sum_j exp(pred[i,j]) over j ranked at-or-after c in a
// stable descending sort of true[i,:]  (computed sort-free via an O(C) scan).
//
// R5: k1 rewritten round-interleaved two-phase. R3/R4 showed the compiler
// refuses to keep the row registers live across the shuffle chain (VGPR=32
// with 8 "live" float4 is impossible) and rematerializes the global loads,
// serializing two memory round-trips per row batch; all variants pinned at
// ~49.5 us (~2.7 TB/s read; docs' 6.29 TB/s "copy" is r+w => read ceiling
// ~3 TB/s). New structure: phase-a wave-norms one row (transient regs),
// phase-b explicit L1/L2-hot re-read with independent loads + LDS inv
// broadcast; per-thread column ownership kills the LDS epilogue combine.
// k2 fused into k3a staging (4-part sum at load).

#define CC 256
#define NN 64
#define DD 1024
#define PARTS 4
#define TK 128   // K-slice for gram split-K

// ---------------- K1: normalize + partial class sums ------------------
// grid = 2*CC*PARTS = 2048 blocks x 256 thr. Block (t,c,p) handles 16 rows
// in 4 rounds of 4; wave w norms row rnd*4+w, then all threads accumulate
// the 4 rows at their own 4 columns. s_inv double-buffered: 1 barrier/round.
__global__ __launch_bounds__(256) void k1_partial(
    const float* __restrict__ emb, const float* __restrict__ feat,
    float* __restrict__ parts /* [2][CC][PARTS][DD] */, float* __restrict__ out)
{
    if (blockIdx.x == 0 && threadIdx.x == 0) out[0] = 0.f;  // for k3b atomics

    int b = blockIdx.x;
    int t = b >> 10;              // tensor
    int c = (b >> 2) & 255;       // class
    int p = b & 3;                // part (16 rows)
    const float* src = (t == 0 ? emb : feat) + ((size_t)c * NN + p * 16) * DD;
    int wave = threadIdx.x >> 6, lane = threadIdx.x & 63;
    int col = threadIdx.x * 4;    // this thread's 4 output columns

    __shared__ float s_inv[2][4];
    float4 acc = make_float4(0.f, 0.f, 0.f, 0.f);

    #pragma unroll
    for (int rnd = 0; rnd < 4; ++rnd) {
        const float* rowbase = src + (size_t)(rnd * 4) * DD;
        // phase a: wave w computes inv-norm of row rnd*4+w (4 KB, fresh read)
        {
            const float* row = rowbase + (size_t)wave * DD;
            float4 v0 = *(const float4*)(row + 0 * 256 + lane * 4);
            float4 v1 = *(const float4*)(row + 1 * 256 + lane * 4);
            float4 v2 = *(const float4*)(row + 2 * 256 + lane * 4);
            float4 v3 = *(const float4*)(row + 3 * 256 + lane * 4);
            float ss = v0.x * v0.x + v0.y * v0.y + v0.z * v0.z + v0.w * v0.w
                     + v1.x * v1.x + v1.y * v1.y + v1.z * v1.z + v1.w * v1.w
                     + v2.x * v2.x + v2.y * v2.y + v2.z * v2.z + v2.w * v2.w
                     + v3.x * v3.x + v3.y * v3.y + v3.z * v3.z + v3.w * v3.w;
            #pragma unroll
            for (int m = 32; m >= 1; m >>= 1)
                ss += __shfl_xor(ss, m, 64);
            if (lane == 0)
                s_inv[rnd & 1][wave] = 1.0f / fmaxf(sqrtf(ss), 1e-12f);
        }
        __syncthreads();
        // phase b: all threads accumulate the 4 rows at own cols (L1/L2-hot,
        // 4 independent loads; next round's phase-a writes the other buffer)
        float i0 = s_inv[rnd & 1][0], i1 = s_inv[rnd & 1][1];
        float i2 = s_inv[rnd & 1][2], i3 = s_inv[rnd & 1][3];
        float4 u0 = *(const float4*)(rowbase + 0 * DD + col);
        float4 u1 = *(const float4*)(rowbase + 1 * DD + col);
        float4 u2 = *(const float4*)(rowbase + 2 * DD + col);
        float4 u3 = *(const float4*)(rowbase + 3 * DD + col);
        acc.x += u0.x * i0 + u1.x * i1 + u2.x * i2 + u3.x * i3;
        acc.y += u0.y * i0 + u1.y * i1 + u2.y * i2 + u3.y * i3;
        acc.z += u0.z * i0 + u1.z * i1 + u2.z * i2 + u3.z * i3;
        acc.w += u0.w * i0 + u1.w * i1 + u2.w * i2 + u3.w * i3;
    }

    *(float4*)(parts + (((size_t)t * CC + c) * PARTS + p) * DD + col) = acc;
}

// ---------------- K3a: split-K tiled Gram partials (k2 fused) ---------
// grid = 2 tensors * 16 tiles(64x64) * 8 K-splits = 256 blocks, 256 thr.
// Stages directly from parts: mean = (sum of 4 parts) / N at load time.
__global__ __launch_bounds__(256) void k3a_gram(
    const float* __restrict__ parts, float* __restrict__ gpart /* [2][8][CC][CC] */)
{
    __shared__ float As[64][132];
    __shared__ float Bs[TK][68];

    int b = blockIdx.x;
    int t = b >> 7;
    int r = b & 127;
    int ks = r >> 4;
    int ti = (r >> 2) & 3, tj = r & 3;
    int i0 = ti * 64, j0 = tj * 64, k0 = ks * TK;
    const float invN = 1.0f / (float)NN;

    for (int f = threadIdx.x; f < 64 * 32; f += 256) {
        int row = f >> 5, c4 = f & 31;
        const float* P = parts + ((size_t)(t * CC + i0 + row) * PARTS) * DD + k0 + c4 * 4;
        float4 v0 = *(const float4*)(P);
        float4 v1 = *(const float4*)(P + DD);
        float4 v2 = *(const float4*)(P + 2 * DD);
        float4 v3 = *(const float4*)(P + 3 * DD);
        float4 v = make_float4((v0.x + v1.x + v2.x + v3.x) * invN,
                               (v0.y + v1.y + v2.y + v3.y) * invN,
                               (v0.z + v1.z + v2.z + v3.z) * invN,
                               (v0.w + v1.w + v2.w + v3.w) * invN);
        *(float4*)&As[row][c4 * 4] = v;
    }
    for (int f = threadIdx.x; f < 64 * 32; f += 256) {
        int row = f >> 5, c4 = f & 31;
        const float* P = parts + ((size_t)(t * CC + j0 + row) * PARTS) * DD + k0 + c4 * 4;
        float4 v0 = *(const float4*)(P);
        float4 v1 = *(const float4*)(P + DD);
        float4 v2 = *(const float4*)(P + 2 * DD);
        float4 v3 = *(const float4*)(P + 3 * DD);
        Bs[c4 * 4 + 0][row] = (v0.x + v1.x + v2.x + v3.x) * invN;
        Bs[c4 * 4 + 1][row] = (v0.y + v1.y + v2.y + v3.y) * invN;
        Bs[c4 * 4 + 2][row] = (v0.z + v1.z + v2.z + v3.z) * invN;
        Bs[c4 * 4 + 3][row] = (v0.w + v1.w + v2.w + v3.w) * invN;
    }
    __syncthreads();

    int tr = threadIdx.x >> 4, tc = threadIdx.x & 15;
    float acc[4][4] = {};
    #pragma unroll 4
    for (int kk = 0; kk < TK; kk += 4) {
        float4 a[4], bb[4];
        #pragma unroll
        for (int q = 0; q < 4; ++q) a[q] = *(float4*)&As[tr * 4 + q][kk];
        #pragma unroll
        for (int kq = 0; kq < 4; ++kq) bb[kq] = *(float4*)&Bs[kk + kq][tc * 4];
        #pragma unroll
        for (int q = 0; q < 4; ++q) {
            acc[q][0] += a[q].x * bb[0].x + a[q].y * bb[1].x + a[q].z * bb[2].x + a[q].w * bb[3].x;
            acc[q][1] += a[q].x * bb[0].y + a[q].y * bb[1].y + a[q].z * bb[2].y + a[q].w * bb[3].y;
            acc[q][2] += a[q].x * bb[0].z + a[q].y * bb[1].z + a[q].z * bb[2].z + a[q].w * bb[3].z;
            acc[q][3] += a[q].x * bb[0].w + a[q].y * bb[1].w + a[q].z * bb[2].w + a[q].w * bb[3].w;
        }
    }

    float* G = gpart + (((size_t)(t * 8 + ks) * CC) + i0 + tr * 4) * CC + j0 + tc * 4;
    #pragma unroll
    for (int q = 0; q < 4; ++q)
        *(float4*)(G + (size_t)q * CC) =
            make_float4(acc[q][0], acc[q][1], acc[q][2], acc[q][3]);
}

// ---------------- K3b: reduce partials + ListMLE + final mean ---------
// grid = CC blocks; one atomicAdd per block into out (zeroed by k1).
__global__ __launch_bounds__(256) void k3b_listmle(
    const float* __restrict__ gpart, float* __restrict__ out)
{
    int i = blockIdx.x, c = threadIdx.x;
    float dp = 0.f, dt = 0.f;
    #pragma unroll
    for (int ks = 0; ks < 8; ++ks) {
        dp += gpart[((size_t)ks * CC + i) * CC + c];
        dt += gpart[((size_t)(8 + ks) * CC + i) * CC + c];
    }

    __shared__ float s_true[CC];
    __shared__ float s_pexp[CC];
    s_true[c] = dt;
    s_pexp[c] = expf(dp);
    __syncthreads();

    // S = sum exp(pred_j) over j ranked at-or-after c (stable desc by true)
    float S = 0.f;
    for (int j = 0; j < CC; ++j) {
        float tj = s_true[j];
        bool take = (tj < dt) || (tj == dt && j >= c);
        S += take ? s_pexp[j] : 0.f;
    }
    float contrib = logf(S + 1e-10f) - dp;

    #pragma unroll
    for (int m = 32; m >= 1; m >>= 1)
        contrib += __shfl_xor(contrib, m, 64);
    __shared__ float s_red[4];
    if ((c & 63) == 0) s_red[c >> 6] = contrib;
    __syncthreads();
    if (c == 0)
        atomicAdd(out, (s_red[0] + s_red[1] + s_red[2] + s_red[3]) * (1.0f / (float)CC));
}

extern "C" void kernel_launch(void* const* d_in, const int* in_sizes, int n_in,
                              void* d_out, int out_size, void* d_ws, size_t ws_size,
                              hipStream_t stream) {
    const float* emb  = (const float*)d_in[0];
    const float* feat = (const float*)d_in[1];
    float* ws = (float*)d_ws;
    float* parts = ws;                                  // 2*CC*PARTS*DD = 8 MiB
    float* gpart = parts + (size_t)2 * CC * PARTS * DD; // 2*8*CC*CC = 4 MiB

    k1_partial <<<2 * CC * PARTS, 256, 0, stream>>>(emb, feat, parts, (float*)d_out);
    k3a_gram   <<<256, 256, 0, stream>>>(parts, gpart);
    k3b_listmle<<<CC, 256, 0, stream>>>(gpart, (float*)d_out);
}